// Round 21
// baseline (121.170 us; speedup 1.0000x reference)
//
#include <hip/hip_runtime.h>
#include <hip/hip_bf16.h>

#define NN 100000   // nodes
#define KN 32       // neighbors per node
#define DD 128      // D_IN == D_OUT
#define TROWS 32              // rows per F tile; 100000 = 3125 * 32 exactly
#define NTILE (NN / TROWS)    // 3125
#define TPB   8               // tiles per block (R17: deeper amortization wins)
#define TBLKS ((NTILE + TPB - 1) / TPB)  // 391
#define NCHUNK 4              // D split into 4 x 32-dim uint8 chunks
#define CDIM 32               // per-chunk table = 3.2MB < 4MB L2
#define GPB   8               // gather node-batches per block (ramp amortization)
#define GBLKS ((NTILE + GPB - 1) / GPB)  // 391 blocks/pass (32 nodes per batch)
#define QSCALE 32.0f
#define DEQ    0.03125f
#define WBF_OFF ((size_t)NCHUNK * NN * CDIM)  // ws offset of bf16 W (32KB)

typedef __attribute__((ext_vector_type(8))) short bf16x8;
typedef __attribute__((ext_vector_type(4))) float f32x4;

__device__ __forceinline__ bf16x8 cvt8(const float4& a, const float4& b) {
  union { bf16x8 v; __hip_bfloat162 p[4]; } u;
  u.p[0] = __float22bfloat162_rn(make_float2(a.x, a.y));
  u.p[1] = __float22bfloat162_rn(make_float2(a.z, a.w));
  u.p[2] = __float22bfloat162_rn(make_float2(b.x, b.y));
  u.p[3] = __float22bfloat162_rn(make_float2(b.z, b.w));
  return u.v;
}

__device__ __forceinline__ unsigned int quant(float x) {
  x = fmaxf(x, 0.f);
  unsigned int q = (unsigned int)__builtin_rintf(x * QSCALE);
  return q > 255u ? 255u : q;
}

__device__ __forceinline__ unsigned int pack4(unsigned int q0, unsigned int q1,
                                              unsigned int q2, unsigned int q3) {
  unsigned int a = __byte_perm(q0, q1, 0x0040);
  unsigned int b = __byte_perm(q2, q3, 0x0040);
  return __byte_perm(a, b, 0x5410);
}

// Kernel 0: wbf = bf16(W), once (~2us). Keeps W L2-hot for fragment preloads.
__global__ __launch_bounds__(256) void k_prep(const float* __restrict__ W,
                                              bf16x8* __restrict__ wbf) {
  const int i = ((int)blockIdx.x * 256 + (int)threadIdx.x) * 8;
  float4 a = *(const float4*)(W + i);
  float4 b = *(const float4*)(W + i + 4);
  wbf[i >> 3] = cvt8(a, b);
}

// Kernel 1: hq[c][node][d] = quant(relu(F @ W^T + b)), chunk-major uint8.
// R17/R18 A/B: TPB=8 (cold-start amortization) is the active lever; W-in-reg
// vs W-in-LDS neutral. This round: TPB=8 AND W-in-registers (32KB LDS only).
// Per iter: stage-next (4 glds, src-swizzled) || compute {8 swizzled
// ds_read_b128, 16 cvt, 16 MFMA, 4 pack+dword stores}; 1 barrier.
// Swapped-operand MFMA (R14): D col=lane&15=node, row-quad=dims.
__global__ __launch_bounds__(256) void k_transform(
    const float* __restrict__ F, const unsigned short* __restrict__ wbf,
    const float* __restrict__ bias, unsigned char* __restrict__ hq) {
  __shared__ __align__(16) float flds[2][TROWS * DD];  // 2 x 16KB
  const int tid = (int)threadIdx.x, lane = tid & 63, w = tid >> 6;
  const int lr = lane & 15, q4 = lane >> 4;
  const int g  = w & 1;          // node group (16 rows)
  const int dh = w >> 1;         // dim half (4 n-tiles = 64 dims)
  const int t0 = (int)blockIdx.x * TPB;

  // ---- stage first F tile (glds, source-swizzled, linear LDS dest) ----
#pragma unroll
  for (int i = 0; i < 4; ++i) {
    const int linear = w * 4096 + i * 1024 + lane * 16;
    const int row = linear >> 9, colb = linear & 511;
    const int scolb = colb ^ ((row & 7) << 4);
    const int srow = min(t0 * TROWS + row, NN - 1);
    __builtin_amdgcn_global_load_lds(
        (const unsigned int*)((const char*)F + (size_t)srow * 512 + scolb),
        (unsigned int*)((char*)flds[0] + w * 4096 + i * 1024), 16, 0, 0);
  }

  // ---- W fragments for this wave's dim-half: 16 x bf16x8 in registers ----
  bf16x8 wfrag[4][4];
#pragma unroll
  for (int n = 0; n < 4; ++n) {
    const unsigned short* bsrc = wbf + (size_t)((dh * 4 + n) * 16 + lr) * DD + q4 * 8;
#pragma unroll
    for (int kt = 0; kt < 4; ++kt)
      wfrag[n][kt] = *(const bf16x8*)(bsrc + kt * 32);
  }
  float4 bb4[4];
#pragma unroll
  for (int n = 0; n < 4; ++n)
    bb4[n] = *(const float4*)(bias + (dh * 4 + n) * 16 + q4 * 4);

  __syncthreads();

  for (int it = 0; it < TPB; ++it) {
    const int t = t0 + it;
    const float* fb = flds[it & 1];

    // stage next tile into the other buffer (overlaps this tile's compute)
    if (it + 1 < TPB && t + 1 < NTILE) {
#pragma unroll
      for (int i = 0; i < 4; ++i) {
        const int linear = w * 4096 + i * 1024 + lane * 16;
        const int row = linear >> 9, colb = linear & 511;
        const int scolb = colb ^ ((row & 7) << 4);
        __builtin_amdgcn_global_load_lds(
            (const unsigned int*)((const char*)F +
                                  (size_t)((t + 1) * TROWS + row) * 512 + scolb),
            (unsigned int*)((char*)flds[(it + 1) & 1] + w * 4096 + i * 1024),
            16, 0, 0);
      }
    }

    if (t < NTILE) {
      // F fragments: rows g*16+lr, swizzled ds_read_b128 + cvt
      const int frow = g * 16 + lr;
      const int fsw = (frow & 7) << 4;
      bf16x8 ffrag[4];
#pragma unroll
      for (int kt = 0; kt < 4; ++kt) {
        const int c0 = (kt * 128 + q4 * 32) ^ fsw;
        const int c1 = (kt * 128 + q4 * 32 + 16) ^ fsw;
        float4 a0 = *(const float4*)((const char*)fb + frow * 512 + c0);
        float4 a1 = *(const float4*)((const char*)fb + frow * 512 + c1);
        ffrag[kt] = cvt8(a0, a1);
      }

      f32x4 acc[4];
#pragma unroll
      for (int n = 0; n < 4; ++n) acc[n] = (f32x4){0.f, 0.f, 0.f, 0.f};
#pragma unroll
      for (int n = 0; n < 4; ++n)
#pragma unroll
        for (int kt = 0; kt < 4; ++kt)
          acc[n] = __builtin_amdgcn_mfma_f32_16x16x32_bf16(
              wfrag[n][kt], ffrag[kt], acc[n], 0, 0, 0);

      const int node = t * TROWS + g * 16 + lr;
#pragma unroll
      for (int n = 0; n < 4; ++n) {
        const int nt = dh * 4 + n;     // n-tile index 0..7
        const unsigned int p = pack4(quant(acc[n][0] + bb4[n].x),
                                     quant(acc[n][1] + bb4[n].y),
                                     quant(acc[n][2] + bb4[n].z),
                                     quant(acc[n][3] + bb4[n].w));
        *(unsigned int*)(hq + ((size_t)(nt >> 1) * NN + node) * CDIM +
                         (nt & 1) * 16 + q4 * 4) = p;
      }
    }
    __syncthreads();  // drains next-tile glds; protects buffer reuse
  }
}

// Kernel 2 (chunk-major, ramp-amortized): out[i][c*32+d] = DEQ*max_j hq[c][nbr][d].
// 4 dispatches (per-chunk 3.2MB table L2-resident, R5-proven). NEW: 391
// blocks x 8 node-batches each -- waves stay resident, dispatch ramp paid
// once per pass instead of per 32-node block (gather occ was 62%).
__global__ __launch_bounds__(256) void k_gather_chunk(
    const int* __restrict__ nbr, const unsigned char* __restrict__ hq,
    float* __restrict__ out, int chunk) {
  const int lane = (int)(threadIdx.x & 63);
  const int wv   = (int)(threadIdx.x >> 6);
  const int g    = lane >> 3;
  const int dp   = lane & 7;
  const unsigned char* tab = hq + (size_t)chunk * NN * CDIM;

  for (int it = 0; it < GPB; ++it) {
    const int n32 = (int)blockIdx.x + it * GBLKS;   // node batch of 32
    if (n32 >= NTILE) break;
    const int node = (n32 * 4 + wv) * 8 + g;

    int nv[4];
#pragma unroll
    for (int s = 0; s < 4; ++s)
      nv[s] = nbr[(size_t)node * KN + s * 8 + dp];

    unsigned int u[KN];
#pragma unroll
    for (int j = 0; j < KN; ++j) {
      const int src = (g << 3) | (j & 7);
      const int idx = __shfl(nv[j >> 3], src);
      u[j] = *(const unsigned int*)(tab + (size_t)idx * CDIM + dp * 4);
    }
    unsigned int m0 = 0u, m1 = 0u, m2 = 0u, m3 = 0u;
#pragma unroll
    for (int j = 0; j < KN; ++j) {
      m0 = max(m0, u[j] & 0xffu);
      m1 = max(m1, (u[j] >> 8) & 0xffu);
      m2 = max(m2, (u[j] >> 16) & 0xffu);
      m3 = max(m3, u[j] >> 24);
    }
    f32x4 r;
    r[0] = (float)m0 * DEQ;
    r[1] = (float)m1 * DEQ;
    r[2] = (float)m2 * DEQ;
    r[3] = (float)m3 * DEQ;
    *(f32x4*)(out + (size_t)node * DD + chunk * CDIM + dp * 4) = r;
  }
}

extern "C" void kernel_launch(void* const* d_in, const int* in_sizes, int n_in,
                              void* d_out, int out_size, void* d_ws, size_t ws_size,
                              hipStream_t stream) {
  const float* F    = (const float*)d_in[0];  // [100000,128] f32
  const int*   nbr  = (const int*)d_in[1];    // [100000,32] i32
  const float* W    = (const float*)d_in[2];  // [128,128] f32
  const float* bias = (const float*)d_in[3];  // [128] f32
  float* out = (float*)d_out;                 // [100000,128] f32
  unsigned char* hq = (unsigned char*)d_ws;   // [4][100000][32] uint8 (12.8 MB)
  unsigned short* wbf = (unsigned short*)((char*)d_ws + WBF_OFF);  // bf16 W

  k_prep<<<8, 256, 0, stream>>>(W, (bf16x8*)wbf);
  k_transform<<<TBLKS, 256, 0, stream>>>(F, wbf, bias, hq);
  for (int c = 0; c < NCHUNK; ++c)
    k_gather_chunk<<<GBLKS, 256, 0, stream>>>(nbr, hq, out, c);
}

// Round 22
// 119.652 us; speedup vs baseline: 1.0127x; 1.0127x over previous
//
#include <hip/hip_runtime.h>
#include <hip/hip_bf16.h>

#define NN 100000   // nodes
#define KN 32       // neighbors per node
#define DD 128      // D_IN == D_OUT
#define TROWS 32              // rows per F tile; 100000 = 3125 * 32 exactly
#define NTILE (NN / TROWS)    // 3125
#define TPB   8               // tiles per block (R17/R21: amortization lever)
#define TBLKS ((NTILE + TPB - 1) / TPB)  // 391
#define NCHUNK 4              // D split into 4 x 32-dim uint8 chunks
#define CDIM 32               // per-chunk table = 3.2MB < 4MB L2
#define GBLKS ((NN + 127) / 128)  // 782 gather blocks of 1024 threads (128 nodes)
#define QSCALE 32.0f
#define DEQ    0.03125f
#define WBF_OFF ((size_t)NCHUNK * NN * CDIM)  // ws offset of bf16 W (32KB)

typedef __attribute__((ext_vector_type(8))) short bf16x8;
typedef __attribute__((ext_vector_type(4))) float f32x4;

__device__ __forceinline__ bf16x8 cvt8(const float4& a, const float4& b) {
  union { bf16x8 v; __hip_bfloat162 p[4]; } u;
  u.p[0] = __float22bfloat162_rn(make_float2(a.x, a.y));
  u.p[1] = __float22bfloat162_rn(make_float2(a.z, a.w));
  u.p[2] = __float22bfloat162_rn(make_float2(b.x, b.y));
  u.p[3] = __float22bfloat162_rn(make_float2(b.z, b.w));
  return u.v;
}

__device__ __forceinline__ unsigned int quant(float x) {
  x = fmaxf(x, 0.f);
  unsigned int q = (unsigned int)__builtin_rintf(x * QSCALE);
  return q > 255u ? 255u : q;
}

__device__ __forceinline__ unsigned int pack4(unsigned int q0, unsigned int q1,
                                              unsigned int q2, unsigned int q3) {
  unsigned int a = __byte_perm(q0, q1, 0x0040);
  unsigned int b = __byte_perm(q2, q3, 0x0040);
  return __byte_perm(a, b, 0x5410);
}

// Kernel 0: wbf = bf16(W), once (~2us). Keeps W L2-hot for fragment preloads.
__global__ __launch_bounds__(256) void k_prep(const float* __restrict__ W,
                                              bf16x8* __restrict__ wbf) {
  const int i = ((int)blockIdx.x * 256 + (int)threadIdx.x) * 8;
  float4 a = *(const float4*)(W + i);
  float4 b = *(const float4*)(W + i + 4);
  wbf[i >> 3] = cvt8(a, b);
}

// Kernel 1: hq[c][node][d] = quant(relu(F @ W^T + b)), chunk-major uint8.
// R21's transform unchanged (measured ~30us, equal to R17's W-LDS variant):
// TPB=8 cold-start amortization, W fragments in registers, 32KB LDS
// (F double-buffer only), swapped-operand MFMA, dword epilogue.
__global__ __launch_bounds__(256) void k_transform(
    const float* __restrict__ F, const unsigned short* __restrict__ wbf,
    const float* __restrict__ bias, unsigned char* __restrict__ hq) {
  __shared__ __align__(16) float flds[2][TROWS * DD];  // 2 x 16KB
  const int tid = (int)threadIdx.x, lane = tid & 63, w = tid >> 6;
  const int lr = lane & 15, q4 = lane >> 4;
  const int g  = w & 1;          // node group (16 rows)
  const int dh = w >> 1;         // dim half (4 n-tiles = 64 dims)
  const int t0 = (int)blockIdx.x * TPB;

  // ---- stage first F tile (glds, source-swizzled, linear LDS dest) ----
#pragma unroll
  for (int i = 0; i < 4; ++i) {
    const int linear = w * 4096 + i * 1024 + lane * 16;
    const int row = linear >> 9, colb = linear & 511;
    const int scolb = colb ^ ((row & 7) << 4);
    const int srow = min(t0 * TROWS + row, NN - 1);
    __builtin_amdgcn_global_load_lds(
        (const unsigned int*)((const char*)F + (size_t)srow * 512 + scolb),
        (unsigned int*)((char*)flds[0] + w * 4096 + i * 1024), 16, 0, 0);
  }

  // ---- W fragments for this wave's dim-half: 16 x bf16x8 in registers ----
  bf16x8 wfrag[4][4];
#pragma unroll
  for (int n = 0; n < 4; ++n) {
    const unsigned short* bsrc = wbf + (size_t)((dh * 4 + n) * 16 + lr) * DD + q4 * 8;
#pragma unroll
    for (int kt = 0; kt < 4; ++kt)
      wfrag[n][kt] = *(const bf16x8*)(bsrc + kt * 32);
  }
  float4 bb4[4];
#pragma unroll
  for (int n = 0; n < 4; ++n)
    bb4[n] = *(const float4*)(bias + (dh * 4 + n) * 16 + q4 * 4);

  __syncthreads();

  for (int it = 0; it < TPB; ++it) {
    const int t = t0 + it;
    const float* fb = flds[it & 1];

    if (it + 1 < TPB && t + 1 < NTILE) {
#pragma unroll
      for (int i = 0; i < 4; ++i) {
        const int linear = w * 4096 + i * 1024 + lane * 16;
        const int row = linear >> 9, colb = linear & 511;
        const int scolb = colb ^ ((row & 7) << 4);
        __builtin_amdgcn_global_load_lds(
            (const unsigned int*)((const char*)F +
                                  (size_t)((t + 1) * TROWS + row) * 512 + scolb),
            (unsigned int*)((char*)flds[(it + 1) & 1] + w * 4096 + i * 1024),
            16, 0, 0);
      }
    }

    if (t < NTILE) {
      const int frow = g * 16 + lr;
      const int fsw = (frow & 7) << 4;
      bf16x8 ffrag[4];
#pragma unroll
      for (int kt = 0; kt < 4; ++kt) {
        const int c0 = (kt * 128 + q4 * 32) ^ fsw;
        const int c1 = (kt * 128 + q4 * 32 + 16) ^ fsw;
        float4 a0 = *(const float4*)((const char*)fb + frow * 512 + c0);
        float4 a1 = *(const float4*)((const char*)fb + frow * 512 + c1);
        ffrag[kt] = cvt8(a0, a1);
      }

      f32x4 acc[4];
#pragma unroll
      for (int n = 0; n < 4; ++n) acc[n] = (f32x4){0.f, 0.f, 0.f, 0.f};
#pragma unroll
      for (int n = 0; n < 4; ++n)
#pragma unroll
        for (int kt = 0; kt < 4; ++kt)
          acc[n] = __builtin_amdgcn_mfma_f32_16x16x32_bf16(
              wfrag[n][kt], ffrag[kt], acc[n], 0, 0, 0);

      const int node = t * TROWS + g * 16 + lr;
#pragma unroll
      for (int n = 0; n < 4; ++n) {
        const int nt = dh * 4 + n;     // n-tile index 0..7
        const unsigned int p = pack4(quant(acc[n][0] + bb4[n].x),
                                     quant(acc[n][1] + bb4[n].y),
                                     quant(acc[n][2] + bb4[n].z),
                                     quant(acc[n][3] + bb4[n].w));
        *(unsigned int*)(hq + ((size_t)(nt >> 1) * NN + node) * CDIM +
                         (nt & 1) * 16 + q4 * 4) = p;
      }
    }
    __syncthreads();  // drains next-tile glds; protects buffer reuse
  }
}

// Kernel 2 (chunk-major, 1024-thread blocks): out[i][c*32+d] = DEQ*max hq[...].
// R21 lesson: gather is latency/request-rate bound -> TLP is king (GPB=8
// regressed -20us). This round: R10's dispatch shape but 16 waves/block
// (782 blocks/pass) to raise resident waves per CU (occ was 62% @ 256-thr).
// Per 8-lane group: one node; 32 x 32B L2-resident table reads; int max;
// dequant after (monotone). Tail groups (node>=NN) uniformly inactive; shfl
// sources stay within the group.
__global__ __launch_bounds__(1024) void k_gather_chunk(
    const int* __restrict__ nbr, const unsigned char* __restrict__ hq,
    float* __restrict__ out, int chunk) {
  const int tid  = (int)threadIdx.x;
  const int lane = tid & 63;
  const int wv   = tid >> 6;         // wave 0..15
  const int g    = lane >> 3;        // node group 0..7
  const int dp   = lane & 7;         // uchar4 within 32B chunk row
  const int node = ((int)blockIdx.x * 16 + wv) * 8 + g;
  if (node >= NN) return;

  int nv[4];
#pragma unroll
  for (int s = 0; s < 4; ++s)
    nv[s] = nbr[(size_t)node * KN + s * 8 + dp];

  const unsigned char* tab = hq + (size_t)chunk * NN * CDIM;
  unsigned int u[KN];
#pragma unroll
  for (int j = 0; j < KN; ++j) {
    const int src = (g << 3) | (j & 7);
    const int idx = __shfl(nv[j >> 3], src);
    u[j] = *(const unsigned int*)(tab + (size_t)idx * CDIM + dp * 4);
  }
  unsigned int m0 = 0u, m1 = 0u, m2 = 0u, m3 = 0u;
#pragma unroll
  for (int j = 0; j < KN; ++j) {
    m0 = max(m0, u[j] & 0xffu);
    m1 = max(m1, (u[j] >> 8) & 0xffu);
    m2 = max(m2, (u[j] >> 16) & 0xffu);
    m3 = max(m3, u[j] >> 24);
  }
  f32x4 r;
  r[0] = (float)m0 * DEQ;
  r[1] = (float)m1 * DEQ;
  r[2] = (float)m2 * DEQ;
  r[3] = (float)m3 * DEQ;
  *(f32x4*)(out + (size_t)node * DD + chunk * CDIM + dp * 4) = r;
}

extern "C" void kernel_launch(void* const* d_in, const int* in_sizes, int n_in,
                              void* d_out, int out_size, void* d_ws, size_t ws_size,
                              hipStream_t stream) {
  const float* F    = (const float*)d_in[0];  // [100000,128] f32
  const int*   nbr  = (const int*)d_in[1];    // [100000,32] i32
  const float* W    = (const float*)d_in[2];  // [128,128] f32
  const float* bias = (const float*)d_in[3];  // [128] f32
  float* out = (float*)d_out;                 // [100000,128] f32
  unsigned char* hq = (unsigned char*)d_ws;   // [4][100000][32] uint8 (12.8 MB)
  unsigned short* wbf = (unsigned short*)((char*)d_ws + WBF_OFF);  // bf16 W

  k_prep<<<8, 256, 0, stream>>>(W, (bf16x8*)wbf);
  k_transform<<<TBLKS, 256, 0, stream>>>(F, wbf, bias, hq);
  for (int c = 0; c < NCHUNK; ++c)
    k_gather_chunk<<<GBLKS, 1024, 0, stream>>>(nbr, hq, out, c);
}

// Round 23
// 99.723 us; speedup vs baseline: 1.2151x; 1.1998x over previous
//
#include <hip/hip_runtime.h>
#include <hip/hip_bf16.h>

#define NN 100000   // nodes
#define KN 32       // neighbors per node
#define DD 128      // D_IN == D_OUT
#define TROWS 32              // rows per F tile; 100000 = 3125 * 32 exactly
#define NTILE (NN / TROWS)    // 3125
#define TBLKS 391             // persistent-ish grid (~1.5 blocks/CU)
#define TPB   8               // tiles per block: 391*8 = 3128 >= 3125
#define NCHUNK 4              // D split into 4 x 32-dim uint8 chunks
#define CDIM 32               // per-chunk table = 3.2MB < 4MB L2
#define QSCALE 32.0f
#define DEQ    0.03125f

typedef __attribute__((ext_vector_type(8))) short bf16x8;
typedef __attribute__((ext_vector_type(4))) float f32x4;

__device__ __forceinline__ bf16x8 cvt8(const float4& a, const float4& b) {
  union { bf16x8 v; __hip_bfloat162 p[4]; } u;
  u.p[0] = __float22bfloat162_rn(make_float2(a.x, a.y));
  u.p[1] = __float22bfloat162_rn(make_float2(a.z, a.w));
  u.p[2] = __float22bfloat162_rn(make_float2(b.x, b.y));
  u.p[3] = __float22bfloat162_rn(make_float2(b.z, b.w));
  return u.v;
}

__device__ __forceinline__ unsigned int quant(float x) {
  x = fmaxf(x, 0.f);
  unsigned int q = (unsigned int)__builtin_rintf(x * QSCALE);
  return q > 255u ? 255u : q;
}

__device__ __forceinline__ unsigned int pack4(unsigned int q0, unsigned int q1,
                                              unsigned int q2, unsigned int q3) {
  unsigned int a = __byte_perm(q0, q1, 0x0040);
  unsigned int b = __byte_perm(q2, q3, 0x0040);
  return __byte_perm(a, b, 0x5410);
}

// Kernel 1: hq[c][node][d] = quant(relu(F @ W^T + b)), chunk-major uint8.
// Best-known transform (R17, measured ~30us): 391 blocks x 8 tiles,
// double-buffered 2-phase loop {stage(t+1) || compute(t); barrier}; W staged
// once per block into LDS (f32->bf16, swizzled ds_writes); F staged via
// global_load_lds (source-swizzled, linear dest, rule 21). Swapped-operand
// MFMA (R14): D col=lane&15=node, row-quad=dims -> dword epilogue.
__global__ __launch_bounds__(256) void k_transform(
    const float* __restrict__ F, const float* __restrict__ W,
    const float* __restrict__ bias, unsigned char* __restrict__ hq) {
  __shared__ __align__(16) unsigned short wlds[DD * DD];      // 32KB bf16 W
  __shared__ __align__(16) float flds[2][TROWS * DD];         // 2 x 16KB F
  const int tid = (int)threadIdx.x, lane = tid & 63, w = tid >> 6;
  const int lr = lane & 15, q4 = lane >> 4;
  const int g  = w & 1;          // node group (16 nodes each)
  const int dh = w >> 1;         // dim half (64 dims = 4 n-tiles)

  // ---- stage W once: thread (row=tid>>1, half=tid&1) cvt-copies 128B ----
  {
    const int row = tid >> 1, half = tid & 1;
    const float* src = W + row * DD + half * 64;
    const int swz = (row & 7) << 4;
#pragma unroll
    for (int i = 0; i < 8; ++i) {
      float4 a = *(const float4*)(src + i * 8);
      float4 b = *(const float4*)(src + i * 8 + 4);
      const int cb = (half * 128 + i * 16) ^ swz;
      *(bf16x8*)((char*)wlds + row * 256 + cb) = cvt8(a, b);
    }
  }

  // ---- first F tile stage (glds, source-swizzled, linear LDS dest) ----
  const int t0 = (int)blockIdx.x * TPB;
#pragma unroll
  for (int i = 0; i < 4; ++i) {
    const int linear = w * 4096 + i * 1024 + lane * 16;
    const int row = linear >> 9, colb = linear & 511;
    const int scolb = colb ^ ((row & 7) << 4);
    __builtin_amdgcn_global_load_lds(
        (const unsigned int*)((const char*)F + (size_t)(t0 * TROWS + row) * 512 + scolb),
        (unsigned int*)((char*)flds[0] + w * 4096 + i * 1024), 16, 0, 0);
  }

  // ---- hoisted bias: float4 per n-tile for this wave's dims ----
  float4 bb4[4];
#pragma unroll
  for (int n = 0; n < 4; ++n)
    bb4[n] = *(const float4*)(bias + (dh * 4 + n) * 16 + q4 * 4);

  __syncthreads();

  for (int it = 0; it < TPB; ++it) {
    const int t = t0 + it;
    const float* fb = flds[it & 1];

    // stage next tile into the other buffer (overlaps this tile's compute)
    if (it + 1 < TPB && t + 1 < NTILE) {
#pragma unroll
      for (int i = 0; i < 4; ++i) {
        const int linear = w * 4096 + i * 1024 + lane * 16;
        const int row = linear >> 9, colb = linear & 511;
        const int scolb = colb ^ ((row & 7) << 4);
        __builtin_amdgcn_global_load_lds(
            (const unsigned int*)((const char*)F +
                                  (size_t)((t + 1) * TROWS + row) * 512 + scolb),
            (unsigned int*)((char*)flds[(it + 1) & 1] + w * 4096 + i * 1024),
            16, 0, 0);
      }
    }

    if (t < NTILE) {
      // F fragments: rows g*16+lr of this tile, swizzled ds_read_b128
      const int frow = g * 16 + lr;
      const int fsw = (frow & 7) << 4;
      bf16x8 ffrag[4];
#pragma unroll
      for (int kt = 0; kt < 4; ++kt) {
        const int c0 = (kt * 128 + q4 * 32) ^ fsw;
        const int c1 = (kt * 128 + q4 * 32 + 16) ^ fsw;
        float4 a0 = *(const float4*)((const char*)fb + frow * 512 + c0);
        float4 a1 = *(const float4*)((const char*)fb + frow * 512 + c1);
        ffrag[kt] = cvt8(a0, a1);
      }

      f32x4 acc[4];
#pragma unroll
      for (int n = 0; n < 4; ++n) acc[n] = (f32x4){0.f, 0.f, 0.f, 0.f};

      // W fragments from LDS in 2-ntile quarters (VGPR cap)
#pragma unroll
      for (int qh = 0; qh < 2; ++qh) {
        bf16x8 wfrag[2][4];
#pragma unroll
        for (int n = 0; n < 2; ++n) {
          const int wrow = (dh * 4 + qh * 2 + n) * 16 + lr;
          const int wsw = (wrow & 7) << 4;
#pragma unroll
          for (int kt = 0; kt < 4; ++kt) {
            const int cb = (q4 * 16 + kt * 64) ^ wsw;
            wfrag[n][kt] = *(const bf16x8*)((const char*)wlds + wrow * 256 + cb);
          }
        }
#pragma unroll
        for (int n = 0; n < 2; ++n)
#pragma unroll
          for (int kt = 0; kt < 4; ++kt)
            acc[qh * 2 + n] = __builtin_amdgcn_mfma_f32_16x16x32_bf16(
                wfrag[n][kt], ffrag[kt], acc[qh * 2 + n], 0, 0, 0);
      }

      // epilogue: +bias, relu, quant, pack -> 4 dword stores per lane
      const int node = t * TROWS + g * 16 + lr;
#pragma unroll
      for (int n = 0; n < 4; ++n) {
        const int nt = dh * 4 + n;     // n-tile index 0..7
        const unsigned int p = pack4(quant(acc[n][0] + bb4[n].x),
                                     quant(acc[n][1] + bb4[n].y),
                                     quant(acc[n][2] + bb4[n].z),
                                     quant(acc[n][3] + bb4[n].w));
        *(unsigned int*)(hq + ((size_t)(nt >> 1) * NN + node) * CDIM +
                         (nt & 1) * 16 + q4 * 4) = p;
      }
    }
    __syncthreads();  // drains next-tile glds; protects buffer reuse
  }
}

// Kernel 2 (chunk-major, R10-exact — empirically optimal of 3 shapes tried):
// out[i][c*32+d] = DEQ*max_j hq[c][nbr[i][j]][d]. 4 dispatches; per-chunk
// contiguous 3.2MB table L2-resident. Wave = 8 nodes; group g = lane>>3 owns
// one node; lane&7 owns one uchar4; u[32] register load batch.
__global__ __launch_bounds__(256) void k_gather_chunk(
    const int* __restrict__ nbr, const unsigned char* __restrict__ hq,
    float* __restrict__ out, int chunk) {
  const int lane = (int)(threadIdx.x & 63);
  const int wv   = (int)(threadIdx.x >> 6);
  const int g    = lane >> 3;
  const int dp   = lane & 7;
  const int node = ((int)blockIdx.x * 4 + wv) * 8 + g;

  int nv[4];
#pragma unroll
  for (int s = 0; s < 4; ++s)
    nv[s] = nbr[(size_t)node * KN + s * 8 + dp];

  const unsigned char* tab = hq + (size_t)chunk * NN * CDIM;
  unsigned int u[KN];
#pragma unroll
  for (int j = 0; j < KN; ++j) {
    const int src = (g << 3) | (j & 7);
    const int idx = __shfl(nv[j >> 3], src);
    u[j] = *(const unsigned int*)(tab + (size_t)idx * CDIM + dp * 4);
  }
  unsigned int m0 = 0u, m1 = 0u, m2 = 0u, m3 = 0u;
#pragma unroll
  for (int j = 0; j < KN; ++j) {
    m0 = max(m0, u[j] & 0xffu);
    m1 = max(m1, (u[j] >> 8) & 0xffu);
    m2 = max(m2, (u[j] >> 16) & 0xffu);
    m3 = max(m3, u[j] >> 24);
  }
  f32x4 r;
  r[0] = (float)m0 * DEQ;
  r[1] = (float)m1 * DEQ;
  r[2] = (float)m2 * DEQ;
  r[3] = (float)m3 * DEQ;
  *(f32x4*)(out + (size_t)node * DD + chunk * CDIM + dp * 4) = r;
}

extern "C" void kernel_launch(void* const* d_in, const int* in_sizes, int n_in,
                              void* d_out, int out_size, void* d_ws, size_t ws_size,
                              hipStream_t stream) {
  const float* F    = (const float*)d_in[0];  // [100000,128] f32
  const int*   nbr  = (const int*)d_in[1];    // [100000,32] i32
  const float* W    = (const float*)d_in[2];  // [128,128] f32
  const float* bias = (const float*)d_in[3];  // [128] f32
  float* out = (float*)d_out;                 // [100000,128] f32
  unsigned char* hq = (unsigned char*)d_ws;   // [4][100000][32] uint8 (12.8 MB)

  k_transform<<<TBLKS, 256, 0, stream>>>(F, W, bias, hq);
  for (int c = 0; c < NCHUNK; ++c)
    k_gather_chunk<<<NN / 32, 256, 0, stream>>>(nbr, hq, out, c);
}